// Round 4
// baseline (192.836 us; speedup 1.0000x reference)
//
#include <hip/hip_runtime.h>
#include <math.h>

// Problem constants (fixed): B=4, C=256, H=64, W=128, D=4, 81 shifts, C/R=16
// out: [B, 81, H, W] fp32 (2,654,208 elements)
// ws (floats): [0) pooled 82,944  [82944) At 82,944  [165888) cpart 2,654,208

#define HH 64
#define WW 128
#define CC 256
#define BB 4

// ---------------------------------------------------------------------------
// Kernel A: pooled[b, s, c] = sum_{h,w} f1[b,c,h,w] * f2pad[b,c,h+i,w+j]
// One 576-thread block (9 waves) per (b,c) plane; thread (h=t/9, di=t%9)
// owns a full row. UNCHANGED.
// ---------------------------------------------------------------------------
__global__ __launch_bounds__(576) void corr_pool_kernel(
    const float* __restrict__ f1, const float* __restrict__ f2,
    float* __restrict__ pooled) {
  const int t  = threadIdx.x;
  const int bc = blockIdx.x;                    // b*256 + c
  const float* f1p = f1 + (size_t)bc * (HH * WW);
  const float* f2p = f2 + (size_t)bc * (HH * WW);

  __shared__ float4 f2s4[72 * 35];              // 40,320 B; reused for reduce

  // --- stage f2 plane with zero halo (single barrier) ---
  const float4 z4 = make_float4(0.f, 0.f, 0.f, 0.f);
  for (int u = t; u < 72 * 35; u += 576) {
    const int rl = u / 35, k = u - rl * 35;     // padded row, padded chunk
    const int gr = rl - 4;                      // f2 row
    float4 v = z4;
    if ((unsigned)gr < 64u && k >= 1 && k <= 32)
      v = *(const float4*)(f2p + (gr << 7) + ((k - 1) << 2));
    f2s4[u] = v;
  }
  __syncthreads();

  // --- stage 1: thread (h, di) accumulates s9[j] over its full row ---
  const int h  = t / 9;                         // 0..63
  const int di = t - h * 9;                     // 0..8
  const float4* f2row = &f2s4[(h + di) * 35];   // padded row h+di
  const float* f1row  = f1p + (h << 7);

  float s9[9];
#pragma unroll
  for (int j = 0; j < 9; ++j) s9[j] = 0.f;

  alignas(16) float f1c[16], f2wc[24];
#pragma unroll
  for (int m = 0; m < 4; ++m)
    *(float4*)&f1c[4 * m] = *(const float4*)(f1row + (m << 2));
#pragma unroll
  for (int m = 0; m < 6; ++m) *(float4*)&f2wc[4 * m] = f2row[m];

  for (int seg = 0; seg < 8; ++seg) {
    const int nxt = (seg < 7) ? seg + 1 : 7;    // clamped (dup load on last)
    alignas(16) float f1n[16], f2wn[24];
#pragma unroll
    for (int m = 0; m < 4; ++m)
      *(float4*)&f1n[4 * m] =
          *(const float4*)(f1row + (nxt << 4) + (m << 2));
#pragma unroll
    for (int m = 0; m < 6; ++m) *(float4*)&f2wn[4 * m] = f2row[(nxt << 2) + m];

#pragma unroll
    for (int k = 0; k < 16; ++k) {
      const float a = f1c[k];
#pragma unroll
      for (int j = 0; j < 9; ++j) s9[j] += a * f2wc[k + j];
    }
#pragma unroll
    for (int m = 0; m < 16; ++m) f1c[m] = f1n[m];
#pragma unroll
    for (int m = 0; m < 24; ++m) f2wc[m] = f2wn[m];
  }

  // --- stage 2: parallel column reduction (all 576 threads) ---
  __syncthreads();                              // stage-1 LDS reads done
  float* red  = (float*)f2s4;                   // [64][81]
  float* red2 = red + 64 * 81;                  // [7][81]
#pragma unroll
  for (int j = 0; j < 9; ++j) red[h * 81 + di * 9 + j] = s9[j];
  __syncthreads();

  if (t < 567) {                                // 7 groups x 81 cols
    const int col = t % 81, g = t / 81;
    const int r0 = g * 9, r1 = (g == 6) ? 64 : r0 + 9;
    float acc = 0.f;
#pragma unroll 3
    for (int rr = r0; rr < r1; ++rr) acc += red[rr * 81 + col];
    red2[g * 81 + col] = acc;
  }
  __syncthreads();

  if (t < 81) {
    float acc = 0.f;
#pragma unroll
    for (int g = 0; g < 7; ++g) acc += red2[g * 81 + t];
    const int b = bc >> 8, c = bc & 255;
    pooled[(size_t)(b * 81 + t) * 256 + c] = acc;   // raw sum (/8192 in B)
  }
}

// ---------------------------------------------------------------------------
// Kernel B: At[b, c, s] = sigmoid(MLP(pooled/8192)). Transposed output for
// kernel C's wave-uniform coefficient s_loads. UNCHANGED.
// ---------------------------------------------------------------------------
__global__ __launch_bounds__(256) void mlp_kernel(
    const float* __restrict__ pooled, const float* __restrict__ w1,
    const float* __restrict__ b1, const float* __restrict__ w2,
    const float* __restrict__ b2, float* __restrict__ At) {
  const int bs = blockIdx.x;                    // b*81 + s
  const int t  = threadIdx.x;
  const int b  = bs / 81;
  const int s  = bs - b * 81;
  __shared__ float p[256];
  __shared__ float hid[16];

  p[t] = pooled[(size_t)bs * 256 + t] * (1.0f / 8192.0f);
  __syncthreads();

  const int g = t >> 4, ln = t & 15;
  float acc = 0.f;
#pragma unroll
  for (int m = 0; m < 16; ++m) {
    const int c = (m << 4) + ln;
    acc += w1[(g << 8) + c] * p[c];
  }
  acc += __shfl_xor(acc, 1);
  acc += __shfl_xor(acc, 2);
  acc += __shfl_xor(acc, 4);
  acc += __shfl_xor(acc, 8);
  if (ln == 0) hid[g] = acc + b1[g];
  __syncthreads();

  float acc2 = b2[t];
#pragma unroll
  for (int k = 0; k < 16; ++k) acc2 += w2[(t << 4) + k] * hid[k];
  const float sv = 1.0f / (1.0f + __expf(-acc2));
  At[((size_t)(b * 256 + t)) * 81 + s] = sv;    // transposed: [b][c][81]
}

// ---------------------------------------------------------------------------
// Async 16B global->LDS copy: lane l's 16B at gptr lands at ldsbase + l*16.
// No VGPR destination -> the compiler CANNOT serialize it behind the consume.
// ---------------------------------------------------------------------------
__device__ __forceinline__ void async16(const float* g, void* lds) {
  __builtin_amdgcn_global_load_lds(
      (const __attribute__((address_space(1))) void*)g,
      (__attribute__((address_space(3))) void*)lds, 16, 0, 0);
}

// ---------------------------------------------------------------------------
// Kernel C: channel-half partial of
//   out[b, i*9+j, h, w] = (1/256) sum_c At[b,c,i*9+j]*f1[c,h,w]*f2[c,h+i-4,w+j-4]
// 2304 single-wave blocks. Round-13: ASYNC LDS PIPELINE (T3/T4). Evidence
// chain: r0/r3 both ~63us with 8 vs 4 loads/iter (TA/L2-BW exonerated);
// r1 more waves -> worse; r2 register pipeline re-serialized (VGPR tell).
// Per-wave iteration = ~2360 cy of which only ~350 is VALU issue: each iter
// pays full queued memory latency because the compiler emits
// batch-load -> waitcnt -> consume. Fix: all 4 streams (f1a,f1b,f2a,f2b
// center rows) via __builtin_amdgcn_global_load_lds into a 2-buffer LDS
// ping-pong; per iter issue c+1's 4 loads, then inline-asm
// s_waitcnt vmcnt(4) (c's loads done, c+1's stay IN FLIGHT across the
// whole FMA block -- never vmcnt(0) in-loop). Window left/right float4s
// come from neighbor lanes' LDS slots (replaces r3's 16 shuffles).
// Single-wave block -> no barriers needed at all.
// Success tell: dur ~30-40us, VALUBusy 65-80%. Failure tell (compiler
// inserted its own vmcnt(0) drain before ds_read): dur ~60 flat -> next
// round goes full inline-asm loop.
// ---------------------------------------------------------------------------
__global__ __launch_bounds__(64, 4) void out_kernel(
    const float* __restrict__ f1, const float* __restrict__ f2,
    const float* __restrict__ At, float* __restrict__ out,
    float* __restrict__ part) {
  // bid = x + 8*(i + 9*tq); tile = tq*8 + x keeps i-siblings on one XCD
  const int bid  = blockIdx.x;
  const int x    = bid & 7;
  const int q    = bid >> 3;                    // 0..287
  const int i    = q % 9;
  const int tq   = q / 9;                       // 0..31
  const int tile = tq * 8 + x;                  // 0..255
  const int half = tile & 1;
  const int rt   = (tile >> 1) & 31;
  const int b    = tile >> 6;
  const int h0   = rt << 1;

  const int t    = threadIdx.x;
  const int r    = t >> 5;                      // 0..1
  const int cidx = t & 31;
  const int w0   = cidx << 2;
  const int h    = h0 + r;
  const int hr   = h + i - 4;
  const bool rowok = ((unsigned)hr < 64u);

  // [buf][stream: f1a,f1b,f2a,f2b][lane] -- 8 KB
  __shared__ float4 sb[2][4][64];

  float acc[9][4];
#pragma unroll
  for (int j = 0; j < 9; ++j)
#pragma unroll
    for (int k = 0; k < 4; ++k) acc[j][k] = 0.f;

  if (rowok) {
    const int c0 = half << 7;                   // 128-channel half base
    const float* pa1 = f1 + (size_t)b * (CC * 8192) + (size_t)c0 * 8192 +
                       (h << 7) + w0;
    const float* pa2 = f2 + (size_t)b * (CC * 8192) + (size_t)c0 * 8192 +
                       (hr << 7);
    const float* pb1 = pa1 + (size_t)64 * 8192; // paired channel c+64
    const float* pb2 = pa2 + (size_t)64 * 8192;
    const float* Aa  = At + (size_t)b * (CC * 81) + (size_t)c0 * 81 + i * 9;

    const bool vA  = (cidx > 0);
    const bool vC  = (cidx < 31);
    const int lane = t;
    const int lm1  = vA ? lane - 1 : lane;      // clamped within row half
    const int lp1  = vC ? lane + 1 : lane;      // (boundary masked below)

    // --- prologue: prefetch channel pair (0, 64) into buf 0 ---
    async16(pa1,      &sb[0][0][0]);
    async16(pb1,      &sb[0][1][0]);
    async16(pa2 + w0, &sb[0][2][0]);
    async16(pb2 + w0, &sb[0][3][0]);

    for (int c = 0; c < 64; ++c) {
      const int cur = c & 1;
      const int nxt = cur ^ 1;

      // --- issue c+1's 4 loads into buf[nxt] (dup of c=63 at the end) ---
      const int adv = (c < 63) ? 8192 : 0;      // cndmask, no branch
      pa1 += adv; pa2 += adv; pb1 += adv; pb2 += adv;
      async16(pa1,      &sb[nxt][0][0]);
      async16(pb1,      &sb[nxt][1][0]);
      async16(pa2 + w0, &sb[nxt][2][0]);
      async16(pb2 + w0, &sb[nxt][3][0]);

      // --- counted wait: c's 4 loads done; c+1's 4 remain in flight ---
      asm volatile("s_waitcnt vmcnt(4)" ::: "memory");

      // --- consume channel pair (c, c+64) from buf[cur] ---
      const float4 xa = sb[cur][0][lane];
      const float4 xb = sb[cur][1][lane];
      const float4 aA = sb[cur][2][lm1];
      const float4 aB = sb[cur][2][lane];
      const float4 aC = sb[cur][2][lp1];
      const float4 bA = sb[cur][3][lm1];
      const float4 bB = sb[cur][3][lane];
      const float4 bC = sb[cur][3][lp1];

      const float* ca = Aa + (size_t)c * 81;    // wave-uniform -> s_load
      const float* cb = ca + (size_t)64 * 81;

      // --- channel a ---
      alignas(16) float f2ra[12];
      f2ra[0] = vA ? aA.x : 0.f;
      f2ra[1] = vA ? aA.y : 0.f;
      f2ra[2] = vA ? aA.z : 0.f;
      f2ra[3] = vA ? aA.w : 0.f;
      f2ra[4] = aB.x; f2ra[5] = aB.y; f2ra[6] = aB.z; f2ra[7] = aB.w;
      f2ra[8]  = vC ? aC.x : 0.f;
      f2ra[9]  = vC ? aC.y : 0.f;
      f2ra[10] = vC ? aC.z : 0.f;
      f2ra[11] = vC ? aC.w : 0.f;
      alignas(16) const float xxa[4] = {xa.x, xa.y, xa.z, xa.w};

#pragma unroll
      for (int j = 0; j < 9; ++j) {
        const float wj = ca[j];
#pragma unroll
        for (int k = 0; k < 4; ++k) acc[j][k] += wj * (xxa[k] * f2ra[k + j]);
      }

      // --- channel b (c+64) ---
      alignas(16) float f2rb[12];
      f2rb[0] = vA ? bA.x : 0.f;
      f2rb[1] = vA ? bA.y : 0.f;
      f2rb[2] = vA ? bA.z : 0.f;
      f2rb[3] = vA ? bA.w : 0.f;
      f2rb[4] = bB.x; f2rb[5] = bB.y; f2rb[6] = bB.z; f2rb[7] = bB.w;
      f2rb[8]  = vC ? bC.x : 0.f;
      f2rb[9]  = vC ? bC.y : 0.f;
      f2rb[10] = vC ? bC.z : 0.f;
      f2rb[11] = vC ? bC.w : 0.f;
      alignas(16) const float xxb[4] = {xb.x, xb.y, xb.z, xb.w};

#pragma unroll
      for (int j = 0; j < 9; ++j) {
        const float wj = cb[j];
#pragma unroll
        for (int k = 0; k < 4; ++k) acc[j][k] += wj * (xxb[k] * f2rb[k + j]);
      }
    }

    // drain the tail prefetch before the wave exits / LDS reuse
    asm volatile("s_waitcnt vmcnt(0)" ::: "memory");
  }

  float* dst = half ? part : out;
  const float inv = 1.0f / 256.0f;
#pragma unroll
  for (int j = 0; j < 9; ++j) {
    float4 o;
    o.x = acc[j][0] * inv;
    o.y = acc[j][1] * inv;
    o.z = acc[j][2] * inv;
    o.w = acc[j][3] * inv;
    *(float4*)(dst + (((size_t)(b * 81 + i * 9 + j) * 64 + h) << 7) + w0) = o;
  }
}

// ---------------------------------------------------------------------------
// Combine: out += channel-half-1 partial. 663,552 float4s, grid 2592 x 256.
// ---------------------------------------------------------------------------
__global__ __launch_bounds__(256) void combine_kernel(
    float* __restrict__ out, const float* __restrict__ part) {
  const size_t idx = (size_t)blockIdx.x * 256 + threadIdx.x;  // float4 index
  float4* o4       = (float4*)out;
  const float4* p4 = (const float4*)part;
  const float4 a = o4[idx], p = p4[idx];
  float4 rv;
  rv.x = a.x + p.x; rv.y = a.y + p.y; rv.z = a.z + p.z; rv.w = a.w + p.w;
  o4[idx] = rv;
}

// ---------------------------------------------------------------------------
extern "C" void kernel_launch(void* const* d_in, const int* in_sizes, int n_in,
                              void* d_out, int out_size, void* d_ws, size_t ws_size,
                              hipStream_t stream) {
  const float* feat1 = (const float*)d_in[0];
  const float* feat2 = (const float*)d_in[1];
  const float* w1    = (const float*)d_in[2];
  const float* b1    = (const float*)d_in[3];
  const float* w2    = (const float*)d_in[4];
  const float* b2    = (const float*)d_in[5];
  float* out = (float*)d_out;

  float* pooled = (float*)d_ws;                 // 82,944 floats
  float* At     = pooled + 82944;               // 82,944 floats
  float* cpart  = At + 82944;                   // 2,654,208 floats

  corr_pool_kernel<<<1024, 576, 0, stream>>>(feat1, feat2, pooled);
  mlp_kernel<<<4 * 81, 256, 0, stream>>>(pooled, w1, b1, w2, b2, At);
  out_kernel<<<2304, 64, 0, stream>>>(feat1, feat2, At, out, cpart);
  combine_kernel<<<2592, 256, 0, stream>>>(out, cpart);
}